// Round 13
// baseline (100.168 us; speedup 1.0000x reference)
//
#include <hip/hip_runtime.h>
#include <hip/hip_bf16.h>

// Problem constants (B=2, M=2048, HS=1024, K=16 heads, D=64)
#define MM   2048
#define HSZ  1024
#define KH   16
#define DH   64

typedef __attribute__((ext_vector_type(8))) short bf16x8;
typedef __attribute__((ext_vector_type(4))) float f32x4;
typedef __attribute__((ext_vector_type(8))) unsigned short u16x8;

#define GLOAD_LDS16(gp, lp) \
    __builtin_amdgcn_global_load_lds( \
        (const __attribute__((address_space(1))) unsigned int*)(gp), \
        (__attribute__((address_space(3))) unsigned int*)(lp), 16, 0, 0)

__device__ __forceinline__ unsigned short f2bf(float x) {   // RNE (epilogue)
    union { float f; unsigned u; } v; v.f = x;
    unsigned r = v.u + 0x7FFFu + ((v.u >> 16) & 1u);
    return (unsigned short)(r >> 16);
}
__device__ __forceinline__ unsigned short f2bfu(float x) {  // round-half-up (staging, fast)
    union { float f; unsigned u; } v; v.f = x;
    return (unsigned short)((v.u + 0x8000u) >> 16);
}
__device__ __forceinline__ u16x8 pack8(float4 a, float4 b) {
    u16x8 o;
    o[0] = f2bfu(a.x); o[1] = f2bfu(a.y); o[2] = f2bfu(a.z); o[3] = f2bfu(a.w);
    o[4] = f2bfu(b.x); o[5] = f2bfu(b.y); o[6] = f2bfu(b.z); o[7] = f2bfu(b.w);
    return o;
}

// ================= L1: vgemm(f32 in) || span || Wout cvt, one launch =================
// blocks f<2048: even -> vgemm tile f/2; odd -> span block f/2. f>=2048 -> Wout cvt.
__global__ __launch_bounds__(256) void fused1(
    const float* __restrict__ h, const float* __restrict__ Wspan,
    const float* __restrict__ Wval, const float* __restrict__ Wout,
    float* __restrict__ mean_, float* __restrict__ soft_,
    unsigned short* __restrict__ hvT, unsigned short* __restrict__ Wout_bf)
{
    __shared__ __align__(16) char smem[32768];
    int f = blockIdx.x;
    int t = threadIdx.x;

    if (f >= 2048) {                 // ---- Wout f32->bf16, 128 blocks ----
        int bid = f - 2048;
        #pragma unroll
        for (int it = 0; it < 8; ++it) {
            int fi = bid * 2048 + t + it * 256;      // float4 id
            float4 v = *(const float4*)(Wout + (long)fi * 4);
            ushort4 o4;
            o4.x = f2bf(v.x); o4.y = f2bf(v.y); o4.z = f2bf(v.z); o4.w = f2bf(v.w);
            *(ushort4*)(Wout_bf + (long)fi * 4) = o4;
        }
        return;
    }

    if (f & 1) {                     // ---- span projection, f32 (1024 blocks x 4 rows) ----
        float (*hrow)[HSZ] = (float(*)[HSZ])smem;     // 16 KB
        int row0 = (f >> 1) * 4;
        #pragma unroll
        for (int i = 0; i < 4; ++i) {
            int li = t + 256 * i;
            int r = li >> 8, c4 = (li & 255) * 4;
            *(float4*)&hrow[r][c4] = *(const float4*)&h[(long)(row0 + r) * HSZ + c4];
        }
        __syncthreads();
        int o = t >> 3, part = t & 7;
        const float* w = Wspan + o * HSZ;
        float4 acc[4] = {};
        #pragma unroll 4
        for (int i = 0; i < 32; ++i) {
            int c = part * 4 + i * 32;
            float4 wv = *(const float4*)&w[c];
            #pragma unroll
            for (int r = 0; r < 4; ++r) {
                float4 a = *(const float4*)&hrow[r][c];
                acc[r].x += a.x * wv.x; acc[r].y += a.y * wv.y;
                acc[r].z += a.z * wv.z; acc[r].w += a.w * wv.w;
            }
        }
        #pragma unroll
        for (int r = 0; r < 4; ++r) {
            float s = acc[r].x + acc[r].y + acc[r].z + acc[r].w;
            s += __shfl_xor(s, 1, 64);
            s += __shfl_xor(s, 2, 64);
            s += __shfl_xor(s, 4, 64);
            if (part == 0) {
                int m = row0 + r;
                int b = m >> 11, mm = m & 2047;
                int bk = b * KH + (o >> 1);
                if ((o & 1) == 0) {
                    mean_[bk * MM + mm] = (1.f / (1.f + __expf(-s))) * (float)MM;
                } else {
                    float sp = (s > 15.f) ? s : log1pf(__expf(s));
                    soft_[bk * MM + mm] = sp;
                }
            }
        }
        return;
    }

    // ---- vgemm: hvT[bz*1024 + n][m] = sum_c Wval[n,c] * h[bz,m,c], f32 inputs ----
    unsigned short* As = (unsigned short*)smem;            // [2][4096]
    unsigned short* Bs = (unsigned short*)(smem + 16384);  // [2][4096]
    int g = f >> 1;
    int swz = (g & 7) * 128 + (g >> 3);                    // XCD-chunked
    int by = swz & 15; int r_ = swz >> 4;
    int bx = r_ & 31, bz = r_ >> 5;
    int wid = t >> 6, l = t & 63;
    int wr = wid >> 1, wc = wid & 1;
    int lr = l & 15, lhi = l >> 4;

    int srow = t >> 2, sk = (t & 3) * 16;
    const float* Ap = Wval + (long)(by * 64 + srow) * HSZ + sk;
    const float* Bp = h + (long)bz * MM * HSZ + (long)(bx * 64 + srow) * HSZ + sk;
    int c0 = (t & 3) * 2;
    int p0 = ((c0 ^ (srow & 7)) * 8), p1 = (((c0 + 1) ^ (srow & 7)) * 8);
    int wbase = srow * 64;

    #define LOADG(RA, RB, kt) do { \
        _Pragma("unroll") for (int j_ = 0; j_ < 4; ++j_) { \
            RA[j_] = *(const float4*)(Ap + (kt) * 64 + j_ * 4); \
            RB[j_] = *(const float4*)(Bp + (kt) * 64 + j_ * 4); } } while (0)
    #define CVTW(RA, RB, buf) do { \
        *(u16x8*)&As[(buf) * 4096 + wbase + p0] = pack8(RA[0], RA[1]); \
        *(u16x8*)&As[(buf) * 4096 + wbase + p1] = pack8(RA[2], RA[3]); \
        *(u16x8*)&Bs[(buf) * 4096 + wbase + p0] = pack8(RB[0], RB[1]); \
        *(u16x8*)&Bs[(buf) * 4096 + wbase + p1] = pack8(RB[2], RB[3]); } while (0)

    f32x4 acc[2][2] = {};
    #define STEP(buf) do { \
        bf16x8 af[2][2], bfr[2][2]; \
        _Pragma("unroll") for (int kk = 0; kk < 2; ++kk) { \
            int slotx = ((kk * 4 + lhi) ^ (lr & 7)) << 3; \
            _Pragma("unroll") for (int i_ = 0; i_ < 2; ++i_) \
                af[kk][i_] = *(const bf16x8*)&As[(buf) * 4096 + (wr * 32 + i_ * 16 + lr) * 64 + slotx]; \
            _Pragma("unroll") for (int j_ = 0; j_ < 2; ++j_) \
                bfr[kk][j_] = *(const bf16x8*)&Bs[(buf) * 4096 + (wc * 32 + j_ * 16 + lr) * 64 + slotx]; } \
        asm volatile("s_waitcnt lgkmcnt(0)" ::: "memory"); \
        __builtin_amdgcn_sched_barrier(0); \
        _Pragma("unroll") for (int kk = 0; kk < 2; ++kk) \
            _Pragma("unroll") for (int i_ = 0; i_ < 2; ++i_) \
                _Pragma("unroll") for (int j_ = 0; j_ < 2; ++j_) \
                    acc[i_][j_] = __builtin_amdgcn_mfma_f32_16x16x32_bf16(af[kk][i_], bfr[kk][j_], acc[i_][j_], 0, 0, 0); \
    } while (0)

    float4 A0[4], B0[4], A1[4], B1[4];
    LOADG(A0, B0, 0);
    asm volatile("s_waitcnt vmcnt(0)" ::: "memory");
    CVTW(A0, B0, 0);
    LOADG(A1, B1, 1);
    __syncthreads();

    for (int ks = 0; ks < 16; ks += 2) {
        if (ks + 1 < 16) {
            asm volatile("s_waitcnt vmcnt(0)" ::: "memory");
            CVTW(A1, B1, 1);                       // tile ks+1 -> buf1
            if (ks + 2 < 16) LOADG(A0, B0, ks + 2);
        }
        STEP(0);                                   // tile ks
        __syncthreads();
        if (ks + 2 < 16) {
            asm volatile("s_waitcnt vmcnt(0)" ::: "memory");
            CVTW(A0, B0, 0);                       // tile ks+2 -> buf0
            if (ks + 3 < 16) LOADG(A1, B1, ks + 3);
        }
        STEP(1);                                   // tile ks+1
        __syncthreads();
    }
    #undef LOADG
    #undef CVTW
    #undef STEP

    // C/D layout: col = l&15, row = (l>>4)*4 + rr
    long czoff = (long)bz * HSZ * MM;
    int row0 = by * 64, col0 = bx * 64;
    #pragma unroll
    for (int i = 0; i < 2; ++i) {
        int rbase = row0 + wr * 32 + i * 16 + lhi * 4;
        #pragma unroll
        for (int j = 0; j < 2; ++j) {
            int cidx = col0 + wc * 32 + j * 16 + lr;
            #pragma unroll
            for (int rr = 0; rr < 4; ++rr)
                hvT[czoff + (long)(rbase + rr) * MM + cidx] = f2bf(acc[i][j][rr]);
        }
    }
}

// ---------------- shared GEMM core, 64x64 tile (bf16 inputs; used by ogemm) ----------------
#define SROW(li) ((li) >> 3)
#define SCOL(li) ((((li) & 7) ^ (SROW(li) & 7)) * 8)

__device__ __forceinline__ void gemm_core64_f32out(
    unsigned short* __restrict__ AsB, unsigned short* __restrict__ BsB,
    const unsigned short* __restrict__ A, const unsigned short* __restrict__ Bm,
    float* __restrict__ Cv, int N, int Kd, int bx, int by)
{
    int row0 = by * 64;
    int col0 = bx * 64;
    int t = threadIdx.x;
    int wid = t >> 6, l = t & 63;
    int wr = wid >> 1, wc = wid & 1;
    int lr = l & 15, lhi = l >> 4;

    #define STAGE64(buf, k0s) do { \
        unsigned short* As_ = AsB + (buf) * 4096; \
        unsigned short* Bs_ = BsB + (buf) * 4096; \
        int a0 = t, a1 = t + 256; \
        GLOAD_LDS16(A + (long)(row0 + SROW(a0)) * Kd + (k0s) + SCOL(a0), As_ + a0 * 8); \
        GLOAD_LDS16(A + (long)(row0 + SROW(a1)) * Kd + (k0s) + SCOL(a1), As_ + a1 * 8); \
        GLOAD_LDS16(Bm + (long)(col0 + SROW(a0)) * Kd + (k0s) + SCOL(a0), Bs_ + a0 * 8); \
        GLOAD_LDS16(Bm + (long)(col0 + SROW(a1)) * Kd + (k0s) + SCOL(a1), Bs_ + a1 * 8); \
    } while (0)

    f32x4 acc[2][2] = {};
    int nk = Kd >> 6;
    STAGE64(0, 0);
    for (int ks = 0; ks < nk; ++ks) {
        int cur = ks & 1;
        if (ks + 1 < nk) {
            STAGE64(cur ^ 1, (ks + 1) << 6);
            asm volatile("s_waitcnt vmcnt(4)" ::: "memory");
        } else {
            asm volatile("s_waitcnt vmcnt(0)" ::: "memory");
        }
        __builtin_amdgcn_s_barrier();

        bf16x8 af[2][2], bfr[2][2];
        #pragma unroll
        for (int kk = 0; kk < 2; ++kk) {
            int slotx = ((kk * 4 + lhi) ^ (lr & 7)) << 3;
            #pragma unroll
            for (int i = 0; i < 2; ++i)
                af[kk][i] = *(const bf16x8*)(AsB + cur * 4096 + (wr * 32 + i * 16 + lr) * 64 + slotx);
            #pragma unroll
            for (int j = 0; j < 2; ++j)
                bfr[kk][j] = *(const bf16x8*)(BsB + cur * 4096 + (wc * 32 + j * 16 + lr) * 64 + slotx);
        }
        asm volatile("s_waitcnt lgkmcnt(0)" ::: "memory");
        __builtin_amdgcn_sched_barrier(0);
        __builtin_amdgcn_s_barrier();

        #pragma unroll
        for (int kk = 0; kk < 2; ++kk)
            #pragma unroll
            for (int i = 0; i < 2; ++i)
                #pragma unroll
                for (int j = 0; j < 2; ++j)
                    acc[i][j] = __builtin_amdgcn_mfma_f32_16x16x32_bf16(af[kk][i], bfr[kk][j], acc[i][j], 0, 0, 0);
    }
    #undef STAGE64

    #pragma unroll
    for (int i = 0; i < 2; ++i) {
        int rbase = row0 + wr * 32 + i * 16 + lhi * 4;
        #pragma unroll
        for (int j = 0; j < 2; ++j) {
            int cidx = col0 + wc * 32 + j * 16 + lr;
            #pragma unroll
            for (int rr = 0; rr < 4; ++rr)
                Cv[(long)(rbase + rr) * N + cidx] = acc[i][j][rr];
        }
    }
}

__global__ __launch_bounds__(256) void ogemm(
    const unsigned short* __restrict__ att, const unsigned short* __restrict__ Wout_bf,
    float* __restrict__ out)
{
    __shared__ __align__(16) unsigned short As[2][4096];
    __shared__ __align__(16) unsigned short Bs[2][4096];
    int f = blockIdx.x;
    int swz = (f & 7) * 128 + (f >> 3);
    int bx = swz & 15, by = (swz >> 4) & 63;
    gemm_core64_f32out(&As[0][0], &Bs[0][0], att, Wout_bf, out, HSZ, HSZ, bx, by);
}

// ---------------- fused Gaussian attention: in-block LDS sort + dynamic k-range ----------------
__global__ __launch_bounds__(512) void attn_gauss(
    const float* __restrict__ mean_, const float* __restrict__ soft_,
    const unsigned short* __restrict__ hvT, unsigned short* __restrict__ att)
{
    __shared__ __align__(16) char usm[16704];     // sort hist | later V tiles
    __shared__ int permL[2048];
    __shared__ float red[2][8];
    int flat = blockIdx.x;                        // 0..511
    int swz = (flat & 7) * 64 + (flat >> 3);      // XCD-chunked bijection
    int bk = swz >> 4;                            // 0..31
    int qb = swz & 15;                            // 0..15
    int t = threadIdx.x, wid = t >> 6, l = t & 63;
    int b = bk >> 4, head = bk & 15;
    int lr = l & 15, lhi = l >> 4;

    // ---- prologue: counting-sort the head's 2048 rows by mean/64 (threads 0..255) ----
    {
        unsigned short (*hist)[257] = (unsigned short(*)[257])usm;
        int* binTot = (int*)(usm + 16448);
        int* binStart = binTot + 32;
        int bins[8];
        if (t < 256) {
            #pragma unroll
            for (int i = 0; i < 8; ++i) {
                float mq_ = mean_[bk * MM + t * 8 + i];
                int bb = (int)(mq_ * (1.f / 64.f));
                bins[i] = min(31, max(0, bb));
            }
            for (int bb = 0; bb < 32; ++bb) hist[bb][t] = 0;
        }
        __syncthreads();
        if (t < 256) {
            #pragma unroll
            for (int i = 0; i < 8; ++i) hist[bins[i]][t]++;
        }
        __syncthreads();
        if (wid < 4) {
            for (int bb = wid * 8; bb < wid * 8 + 8; ++bb) {
                int carry = 0;
                for (int g = 0; g < 4; ++g) {
                    int v = (int)hist[bb][g * 64 + l];
                    int x = v;
                    #pragma unroll
                    for (int off = 1; off < 64; off <<= 1) {
                        int y = __shfl_up(x, off, 64);
                        if (l >= off) x += y;
                    }
                    hist[bb][g * 64 + l] = (unsigned short)(x - v + carry);
                    carry += __shfl(x, 63, 64);
                }
                if (l == 0) binTot[bb] = carry;
            }
        }
        __syncthreads();
        if (t == 0) {
            int s = 0;
            for (int bb = 0; bb < 32; ++bb) { binStart[bb] = s; s += binTot[bb]; }
        }
        __syncthreads();
        if (t < 256) {
            #pragma unroll
            for (int i = 0; i < 8; ++i) {
                int bb = bins[i];
                int prior = 0;
                #pragma unroll
                for (int j = 0; j < 8; ++j) if (j < i && bins[j] == bb) prior++;
                permL[binStart[bb] + (int)hist[bb][t] + prior] = t * 8 + i;
            }
        }
        __syncthreads();
    }

    unsigned short (*Vs)[4096] = (unsigned short(*)[4096])usm;   // overlays hist
    int slot = qb * 128 + wid * 16 + lr;
    int q = permL[slot];
    float mq = mean_[bk * MM + q];
    float sq = soft_[bk * MM + q];
    const unsigned short* Vbase = hvT + (long)bk * DH * MM;

    // block-level k-tile range from union of per-row windows (exp(-50) cutoff)
    float w = __fsqrt_rn(50.f / sq);
    float lo = mq - w, hi = mq + w;
    #pragma unroll
    for (int off = 1; off < 64; off <<= 1) {
        lo = fminf(lo, __shfl_xor(lo, off, 64));
        hi = fmaxf(hi, __shfl_xor(hi, off, 64));
    }
    if (l == 0) { red[0][wid] = lo; red[1][wid] = hi; }
    __syncthreads();
    float blo = red[0][0], bhi = red[1][0];
    #pragma unroll
    for (int i = 1; i < 8; ++i) {
        blo = fminf(blo, red[0][i]);
        bhi = fmaxf(bhi, red[1][i]);
    }
    blo = fmaxf(blo, 0.f);
    bhi = fmaxf(fminf(bhi, 2047.f), 0.f);
    int kt0 = ((int)blo) >> 6;
    int kt1 = ((int)bhi) >> 6;
    if (kt1 < kt0) kt1 = kt0;

    int sr = t >> 3;
    int sc = (((t & 7) ^ (sr & 7)) * 8);

    f32x4 acc[4] = {};
    float lsum = 0.f;
    int jlane0 = lhi * 8;

    GLOAD_LDS16(Vbase + (long)sr * MM + (kt0 << 6) + sc, &Vs[0][t * 8]);
    __syncthreads();

    for (int kt = kt0; kt <= kt1; ++kt) {
        int cur = (kt - kt0) & 1;
        int k0 = kt << 6;
        if (kt < kt1)
            GLOAD_LDS16(Vbase + (long)sr * MM + (k0 + 64) + sc, &Vs[cur ^ 1][t * 8]);

        float dmin = fmaxf(fmaxf((float)k0 - mq, mq - (float)(k0 + 63)), 0.f);
        bool active = (sq * dmin * dmin) < 50.f;   // exp(-50) ~ 2e-22
        if (__ballot(active)) {
            #pragma unroll
            for (int kk = 0; kk < 64; kk += 32) {
                bf16x8 pfrag;
                float dbase = (float)(k0 + kk + jlane0) - mq;
                #pragma unroll
                for (int jj = 0; jj < 8; ++jj) {
                    float d_ = dbase + (float)jj;
                    float p = __expf(-sq * d_ * d_);
                    lsum += p;
                    pfrag[jj] = (short)f2bf(p);
                }
                int slotx = (((kk >> 3) + lhi) ^ (lr & 7)) << 3;
                #pragma unroll
                for (int df = 0; df < 4; ++df) {
                    bf16x8 vf = *(const bf16x8*)&Vs[cur][(df * 16 + lr) * 64 + slotx];
                    acc[df] = __builtin_amdgcn_mfma_f32_16x16x32_bf16(pfrag, vf, acc[df], 0, 0, 0);
                }
            }
        }
        __syncthreads();
    }

    lsum += __shfl_xor(lsum, 16, 64);
    lsum += __shfl_xor(lsum, 32, 64);

    int slot_base = qb * 128 + wid * 16;
    #pragma unroll
    for (int r_ = 0; r_ < 4; ++r_) {
        int qr = lhi * 4 + r_;
        float inv = 1.f / __shfl(lsum, qr, 64);
        int qo = permL[slot_base + qr];
        long orow = ((long)b * MM + qo) * HSZ + head * DH;
        #pragma unroll
        for (int df = 0; df < 4; ++df)
            att[orow + df * 16 + lr] = f2bf(acc[df][r_] * inv);
    }
}

extern "C" void kernel_launch(void* const* d_in, const int* in_sizes, int n_in,
                              void* d_out, int out_size, void* d_ws, size_t ws_size,
                              hipStream_t stream) {
    (void)in_sizes; (void)n_in; (void)out_size; (void)ws_size;
    const float* h     = (const float*)d_in[0];   // (2, 2048, 1024)
    const float* Wspan = (const float*)d_in[1];   // (32, 1024)
    const float* Wval  = (const float*)d_in[2];   // (1024, 1024)
    const float* Wout  = (const float*)d_in[3];   // (1024, 1024)
    float* out = (float*)d_out;                   // (2, 2048, 1024) f32

    char* ws = (char*)d_ws;
    unsigned short* hvT     = (unsigned short*)(ws);               // 8 MB
    unsigned short* att     = (unsigned short*)(ws +  8388608);    // 8 MB
    unsigned short* Wout_bf = (unsigned short*)(ws + 16777216);    // 2 MB
    float*          mean_   = (float*)(ws + 18874368);             // 256 KB
    float*          soft_   = (float*)(ws + 19136512);             // 256 KB

    // 1. vgemm(f32 in) || span || Wout cvt  (interleaved block ids)
    fused1<<<2176, 256, 0, stream>>>(h, Wspan, Wval, Wout,
                                     mean_, soft_, hvT, Wout_bf);

    // 2. attention with in-block sort -> att (B, M, HS) bf16
    attn_gauss<<<512, 512, 0, stream>>>(mean_, soft_, hvT, att);

    // 3. output GEMM: out[b*2048+m][n] = sum_c att[b,m,c] * Wout[n,c]
    ogemm<<<1024, 256, 0, stream>>>(att, Wout_bf, out);
}

// Round 14
// 69.704 us; speedup vs baseline: 1.4370x; 1.4370x over previous
//
#include <hip/hip_runtime.h>
#include <hip/hip_bf16.h>

// Problem constants (B=2, M=2048, HS=1024, K=16 heads, D=64)
#define MM   2048
#define HSZ  1024
#define KH   16
#define DH   64

typedef __attribute__((ext_vector_type(8))) short bf16x8;
typedef __attribute__((ext_vector_type(4))) float f32x4;
typedef __attribute__((ext_vector_type(8))) unsigned short u16x8;

#define GLOAD_LDS16(gp, lp) \
    __builtin_amdgcn_global_load_lds( \
        (const __attribute__((address_space(1))) unsigned int*)(gp), \
        (__attribute__((address_space(3))) unsigned int*)(lp), 16, 0, 0)

__device__ __forceinline__ unsigned short f2bf(float x) {
    union { float f; unsigned u; } v; v.f = x;
    unsigned r = v.u + 0x7FFFu + ((v.u >> 16) & 1u);
    return (unsigned short)(r >> 16);
}

// ================= L1: span-as-GEMM (blocks 0..63) || converts (64..1599) =================
// span: s = h.w via bf16-split 3-product MFMA (hi*whi + hi*wlo + lo*whi), f32 accum.
// 64 blocks x 64 rows x 32 outputs, K=1024. h read once; Wspan slice staged per K-step.
__global__ __launch_bounds__(256) void pre_fused(
    const float* __restrict__ h, const float* __restrict__ Wspan,
    const float* __restrict__ Wval, const float* __restrict__ Wout,
    float* __restrict__ mean_, float* __restrict__ soft_,
    unsigned short* __restrict__ h_bf,
    unsigned short* __restrict__ Wval_bf, unsigned short* __restrict__ Wout_bf)
{
    __shared__ __align__(16) float As[3][64 * 64];            // 48 KB, 3-buf rotation
    __shared__ __align__(16) unsigned short Whi[2][32 * 64];  // 8 KB
    __shared__ __align__(16) unsigned short Wlo[2][32 * 64];  // 8 KB
    int t = threadIdx.x;

    if (blockIdx.x >= 64) {      // ---- converts: h -> h_bf, Wval/Wout -> bf16 ----
        int bid = blockIdx.x - 64;
        #pragma unroll
        for (int i = 0; i < 4; ++i) {
            int fi = bid * 1024 + i * 256 + t;   // float4 id, 0..1572863
            const float* in; unsigned short* out; int off;
            if (fi < 1048576)      { in = h;    out = h_bf;    off = fi; }
            else if (fi < 1310720) { in = Wval; out = Wval_bf; off = fi - 1048576; }
            else                   { in = Wout; out = Wout_bf; off = fi - 1310720; }
            float4 v = *(const float4*)(in + (long)off * 4);
            ushort4 o4;
            o4.x = f2bf(v.x); o4.y = f2bf(v.y); o4.z = f2bf(v.z); o4.w = f2bf(v.w);
            *(ushort4*)(out + (long)off * 4) = o4;
        }
        return;
    }

    // ---- span GEMM block ----
    int row0 = blockIdx.x * 64;
    int wid = t >> 6, l = t & 63;
    int lr = l & 15, lhi = l >> 4;
    int arow = wid * 16 + lr;                 // A-row within block (per-lane)
    // W staging assignment: thread -> (o, chunk)
    int wo = t >> 3, wc8 = t & 7;
    const float* wsrc = Wspan + wo * 1024 + wc8 * 8;
    int wdst = wo * 64 + ((wc8 ^ (wo & 7)) * 8);

    f32x4 acc[2] = {};
    float4 WA0, WA1, WB0, WB1;                // W register slots (k-step parity)

    #define WLOAD(R0, R1, k0) { R0 = *(const float4*)(wsrc + (k0)); \
                                R1 = *(const float4*)(wsrc + (k0) + 4); }
    #define STAGEA(buf, k0) { \
        _Pragma("unroll") for (int i_ = 0; i_ < 4; ++i_) { \
            int li = t + 256 * i_; int rw = li >> 4; int cs = li & 15; \
            GLOAD_LDS16(h + (long)(row0 + rw) * HSZ + (k0) + ((cs ^ (rw & 15)) * 4), \
                        &As[buf][li * 4]); } }
    #define WWRITE(buf, R0, R1) { \
        float wf_[8] = {R0.x,R0.y,R0.z,R0.w,R1.x,R1.y,R1.z,R1.w}; \
        u16x8 hi8, lo8; \
        _Pragma("unroll") for (int j_ = 0; j_ < 8; ++j_) { \
            unsigned short hu_ = f2bf(wf_[j_]); \
            union { unsigned u; float f; } cv_; cv_.u = (unsigned)hu_ << 16; \
            hi8[j_] = hu_; lo8[j_] = f2bf(wf_[j_] - cv_.f); } \
        *(u16x8*)&Whi[buf][wdst] = hi8; *(u16x8*)&Wlo[buf][wdst] = lo8; }
    #define COMPUTE(abuf, wbuf) { \
        _Pragma("unroll") for (int ksub = 0; ksub < 2; ++ksub) { \
            int c_ = ksub * 8 + lhi * 2; \
            int s0_ = c_ ^ (arow & 15), s1_ = (c_ + 1) ^ (arow & 15); \
            float4 fa_ = *(const float4*)&As[abuf][arow * 64 + s0_ * 4]; \
            float4 fb_ = *(const float4*)&As[abuf][arow * 64 + s1_ * 4]; \
            float af_[8] = {fa_.x,fa_.y,fa_.z,fa_.w,fb_.x,fb_.y,fb_.z,fb_.w}; \
            bf16x8 hh_, hl_; \
            _Pragma("unroll") for (int j_ = 0; j_ < 8; ++j_) { \
                unsigned short hu_ = f2bf(af_[j_]); \
                union { unsigned u; float f; } cv_; cv_.u = (unsigned)hu_ << 16; \
                hh_[j_] = (short)hu_; hl_[j_] = (short)f2bf(af_[j_] - cv_.f); } \
            _Pragma("unroll") for (int ct_ = 0; ct_ < 2; ++ct_) { \
                int orow_ = ct_ * 16 + lr; \
                int ws_ = ((ksub * 4 + lhi) ^ (orow_ & 7)) * 8; \
                bf16x8 wh_ = *(const bf16x8*)&Whi[wbuf][orow_ * 64 + ws_]; \
                bf16x8 wl_ = *(const bf16x8*)&Wlo[wbuf][orow_ * 64 + ws_]; \
                acc[ct_] = __builtin_amdgcn_mfma_f32_16x16x32_bf16(hh_, wh_, acc[ct_], 0, 0, 0); \
                acc[ct_] = __builtin_amdgcn_mfma_f32_16x16x32_bf16(hh_, wl_, acc[ct_], 0, 0, 0); \
                acc[ct_] = __builtin_amdgcn_mfma_f32_16x16x32_bf16(hl_, wh_, acc[ct_], 0, 0, 0); } } }

    // prologue: W(0),A(0),W(1),A(1) in flight; publish buf0
    WLOAD(WA0, WA1, 0);
    STAGEA(0, 0);
    WLOAD(WB0, WB1, 64);
    STAGEA(1, 64);
    asm volatile("s_waitcnt vmcnt(6)" ::: "memory");   // drain W(0)+A(0)
    WWRITE(0, WA0, WA1);
    asm volatile("s_waitcnt lgkmcnt(0)" ::: "memory");
    __builtin_amdgcn_s_barrier();

    #pragma unroll
    for (int ks = 0; ks < 16; ++ks) {
        if (ks + 2 < 16) {
            if ((ks & 1) == 0) { WLOAD(WA0, WA1, (ks + 2) * 64); }  // even k -> slot A
            else               { WLOAD(WB0, WB1, (ks + 2) * 64); }
            STAGEA((ks + 2) % 3, (ks + 2) * 64);
        }
        if (ks + 2 < 16) asm volatile("s_waitcnt vmcnt(4)" ::: "memory");  // drain A(ks+1)+W(ks+2)
        else             asm volatile("s_waitcnt vmcnt(0)" ::: "memory");
        if (ks + 1 < 16) {
            if (ks & 1) WWRITE((ks + 1) & 1, WA0, WA1)              // W(ks+1) odd ks -> slot A
            else        WWRITE((ks + 1) & 1, WB0, WB1)              // even ks -> slot B
        }
        COMPUTE(ks % 3, ks & 1);
        asm volatile("s_waitcnt lgkmcnt(0)" ::: "memory");
        __builtin_amdgcn_s_barrier();
    }
    #undef WLOAD
    #undef STAGEA
    #undef WWRITE
    #undef COMPUTE

    // epilogue: D col = l&15 -> output o; row = lhi*4 + r_
    #pragma unroll
    for (int ct = 0; ct < 2; ++ct) {
        int o = ct * 16 + lr;
        #pragma unroll
        for (int r_ = 0; r_ < 4; ++r_) {
            int m = row0 + wid * 16 + lhi * 4 + r_;
            int b = m >> 11, mm = m & 2047;
            int bk = b * KH + (o >> 1);
            float s = acc[ct][r_];
            if (!(o & 1)) mean_[bk * MM + mm] = (1.f / (1.f + __expf(-s))) * (float)MM;
            else          soft_[bk * MM + mm] = (s > 15.f) ? s : log1pf(__expf(s));
        }
    }
}

// ---------------- shared GEMM core, 64x64 tile (R11, unchanged) ----------------
#define SROW(li) ((li) >> 3)
#define SCOL(li) ((((li) & 7) ^ (SROW(li) & 7)) * 8)

template<int STORE_BF16>
__device__ __forceinline__ void gemm_core64(
    unsigned short* __restrict__ AsB, unsigned short* __restrict__ BsB,   // each [2][4096]
    const unsigned short* __restrict__ A, const unsigned short* __restrict__ Bm,
    void* __restrict__ Cv, int N, int Kd,
    int bx, int by, int bz, long aZ, long bZ, long cZ)
{
    const unsigned short* Ab = A  + bz * aZ;
    const unsigned short* Bb = Bm + bz * bZ;
    long czoff = bz * cZ;
    int row0 = by * 64;
    int col0 = bx * 64;
    int t = threadIdx.x;
    int wid = t >> 6, l = t & 63;
    int wr = wid >> 1, wc = wid & 1;
    int lr = l & 15, lhi = l >> 4;

    #define STAGE64(buf, k0s) do { \
        unsigned short* As_ = AsB + (buf) * 4096; \
        unsigned short* Bs_ = BsB + (buf) * 4096; \
        int a0 = t, a1 = t + 256; \
        GLOAD_LDS16(Ab + (long)(row0 + SROW(a0)) * Kd + (k0s) + SCOL(a0), As_ + a0 * 8); \
        GLOAD_LDS16(Ab + (long)(row0 + SROW(a1)) * Kd + (k0s) + SCOL(a1), As_ + a1 * 8); \
        GLOAD_LDS16(Bb + (long)(col0 + SROW(a0)) * Kd + (k0s) + SCOL(a0), Bs_ + a0 * 8); \
        GLOAD_LDS16(Bb + (long)(col0 + SROW(a1)) * Kd + (k0s) + SCOL(a1), Bs_ + a1 * 8); \
    } while (0)

    f32x4 acc[2][2] = {};
    int nk = Kd >> 6;

    STAGE64(0, 0);

    for (int ks = 0; ks < nk; ++ks) {
        int cur = ks & 1;
        if (ks + 1 < nk) {
            STAGE64(cur ^ 1, (ks + 1) << 6);
            asm volatile("s_waitcnt vmcnt(4)" ::: "memory");
        } else {
            asm volatile("s_waitcnt vmcnt(0)" ::: "memory");
        }
        __builtin_amdgcn_s_barrier();

        bf16x8 af[2][2], bfr[2][2];
        #pragma unroll
        for (int kk = 0; kk < 2; ++kk) {
            int slotx = ((kk * 4 + lhi) ^ (lr & 7)) << 3;
            #pragma unroll
            for (int i = 0; i < 2; ++i)
                af[kk][i] = *(const bf16x8*)(AsB + cur * 4096 + (wr * 32 + i * 16 + lr) * 64 + slotx);
            #pragma unroll
            for (int j = 0; j < 2; ++j)
                bfr[kk][j] = *(const bf16x8*)(BsB + cur * 4096 + (wc * 32 + j * 16 + lr) * 64 + slotx);
        }
        asm volatile("s_waitcnt lgkmcnt(0)" ::: "memory");
        __builtin_amdgcn_sched_barrier(0);
        __builtin_amdgcn_s_barrier();

        #pragma unroll
        for (int kk = 0; kk < 2; ++kk)
            #pragma unroll
            for (int i = 0; i < 2; ++i)
                #pragma unroll
                for (int j = 0; j < 2; ++j)
                    acc[i][j] = __builtin_amdgcn_mfma_f32_16x16x32_bf16(af[kk][i], bfr[kk][j], acc[i][j], 0, 0, 0);
    }
    #undef STAGE64

    #pragma unroll
    for (int i = 0; i < 2; ++i) {
        int rbase = row0 + wr * 32 + i * 16 + lhi * 4;
        #pragma unroll
        for (int j = 0; j < 2; ++j) {
            int cidx = col0 + wc * 32 + j * 16 + lr;
            #pragma unroll
            for (int r_ = 0; r_ < 4; ++r_) {
                long idx = czoff + (long)(rbase + r_) * N + cidx;
                if (STORE_BF16) ((unsigned short*)Cv)[idx] = f2bf(acc[i][j][r_]);
                else            ((float*)Cv)[idx] = acc[i][j][r_];
            }
        }
    }
}

// ---------------- deterministic counting sort of rows by mean/64 (one bk per call) ----------------
__device__ void sort_core(char* smem, const float* __restrict__ mean_,
                          int* __restrict__ perm, int bk)
{
    unsigned short (*hist)[257] = (unsigned short(*)[257])smem;
    int* binTot = (int*)(smem + 16448);
    int* binStart = binTot + 32;
    int t = threadIdx.x;
    int bins[8];
    #pragma unroll
    for (int i = 0; i < 8; ++i) {
        float mq = mean_[bk * MM + t * 8 + i];
        int b = (int)(mq * (1.f / 64.f));
        bins[i] = min(31, max(0, b));
    }
    for (int b = 0; b < 32; ++b) hist[b][t] = 0;
    __syncthreads();
    #pragma unroll
    for (int i = 0; i < 8; ++i) hist[bins[i]][t]++;
    __syncthreads();
    int w = t >> 6, l = t & 63;
    for (int b = w * 8; b < w * 8 + 8; ++b) {
        int carry = 0;
        for (int g = 0; g < 4; ++g) {
            int v = (int)hist[b][g * 64 + l];
            int x = v;
            #pragma unroll
            for (int off = 1; off < 64; off <<= 1) {
                int y = __shfl_up(x, off, 64);
                if (l >= off) x += y;
            }
            hist[b][g * 64 + l] = (unsigned short)(x - v + carry);
            carry += __shfl(x, 63, 64);
        }
        if (l == 0) binTot[b] = carry;
    }
    __syncthreads();
    if (t == 0) {
        int s = 0;
        for (int b = 0; b < 32; ++b) { binStart[b] = s; s += binTot[b]; }
    }
    __syncthreads();
    #pragma unroll
    for (int i = 0; i < 8; ++i) {
        int b = bins[i];
        int prior = 0;
        #pragma unroll
        for (int j = 0; j < 8; ++j) if (j < i && bins[j] == b) prior++;
        int pos = binStart[b] + (int)hist[b][t] + prior;
        perm[bk * MM + pos] = t * 8 + i;
    }
}

// ---------------- value GEMM (blocks 0..1023) + sort (blocks 1024..1055) ----------------
__global__ __launch_bounds__(256) void vgemm_sort(
    const unsigned short* __restrict__ Wval_bf, const unsigned short* __restrict__ h_bf,
    unsigned short* __restrict__ hvT,
    const float* __restrict__ mean_, int* __restrict__ perm)
{
    __shared__ __align__(16) char smem[32768];
    int f = blockIdx.x;
    if (f < 1024) {
        int swz = (f & 7) * 128 + (f >> 3);
        int by = swz & 15, r = swz >> 4;
        int bx = r & 31, bz = r >> 5;
        gemm_core64<1>((unsigned short*)smem, (unsigned short*)(smem + 16384),
                       Wval_bf, h_bf, hvT, MM, HSZ, bx, by, bz,
                       0L, (long)MM * HSZ, (long)HSZ * MM);
    } else {
        sort_core(smem, mean_, perm, f - 1024);
    }
}

// ---------------- output GEMM standalone ----------------
__global__ __launch_bounds__(256) void ogemm(
    const unsigned short* __restrict__ att, const unsigned short* __restrict__ Wout_bf,
    float* __restrict__ out)
{
    __shared__ __align__(16) unsigned short As[2][4096];
    __shared__ __align__(16) unsigned short Bs[2][4096];
    int f = blockIdx.x;
    int swz = (f & 7) * 128 + (f >> 3);
    int bx = swz & 15, by = (swz >> 4) & 63;
    gemm_core64<0>(&As[0][0], &Bs[0][0], att, Wout_bf, out, HSZ, HSZ,
                   bx, by, 0, 0L, 0L, 0L);
}

// ---------------- fused Gaussian attention over mean-sorted rows (dynamic k-range) ----------------
__global__ __launch_bounds__(512) void attn_gauss(
    const float* __restrict__ mean_, const float* __restrict__ soft_,
    const int* __restrict__ perm,
    const unsigned short* __restrict__ hvT, unsigned short* __restrict__ att)
{
    __shared__ __align__(16) unsigned short Vs[2][64 * 64];
    __shared__ float red[2][8];
    int flat = blockIdx.x;                   // 0..511
    int swz = (flat & 7) * 64 + (flat >> 3); // XCD-chunked bijection
    int bk = swz >> 4;                       // 0..31
    int qb = swz & 15;                       // 0..15
    int t = threadIdx.x, wid = t >> 6, l = t & 63;
    int b = bk >> 4, head = bk & 15;
    int lr = l & 15, lhi = l >> 4;
    int slot = qb * 128 + wid * 16 + lr;
    int q = perm[bk * MM + slot];
    float mq  = mean_[bk * MM + q];
    float sq  = soft_[bk * MM + q];
    const unsigned short* Vbase = hvT + (long)bk * DH * MM;

    float w = __fsqrt_rn(50.f / sq);
    float lo = mq - w, hi = mq + w;
    #pragma unroll
    for (int off = 1; off < 64; off <<= 1) {
        lo = fminf(lo, __shfl_xor(lo, off, 64));
        hi = fmaxf(hi, __shfl_xor(hi, off, 64));
    }
    if (l == 0) { red[0][wid] = lo; red[1][wid] = hi; }
    __syncthreads();
    float blo = red[0][0], bhi = red[1][0];
    #pragma unroll
    for (int i = 1; i < 8; ++i) {
        blo = fminf(blo, red[0][i]);
        bhi = fmaxf(bhi, red[1][i]);
    }
    blo = fmaxf(blo, 0.f);
    bhi = fmaxf(fminf(bhi, 2047.f), 0.f);
    int kt0 = ((int)blo) >> 6;
    int kt1 = ((int)bhi) >> 6;
    if (kt1 < kt0) kt1 = kt0;

    int sr = t >> 3;
    int sc = (((t & 7) ^ (sr & 7)) * 8);

    f32x4 acc[4] = {};
    float lsum = 0.f;
    int jlane0 = lhi * 8;

    GLOAD_LDS16(Vbase + (long)sr * MM + (kt0 << 6) + sc, &Vs[0][t * 8]);
    __syncthreads();

    for (int kt = kt0; kt <= kt1; ++kt) {
        int cur = (kt - kt0) & 1;
        int k0 = kt << 6;
        if (kt < kt1)
            GLOAD_LDS16(Vbase + (long)sr * MM + (k0 + 64) + sc, &Vs[cur ^ 1][t * 8]);

        float dmin = fmaxf(fmaxf((float)k0 - mq, mq - (float)(k0 + 63)), 0.f);
        bool active = (sq * dmin * dmin) < 50.f;   // exp(-50) ~ 2e-22
        if (__ballot(active)) {
            #pragma unroll
            for (int kk = 0; kk < 64; kk += 32) {
                bf16x8 pfrag;
                float dbase = (float)(k0 + kk + jlane0) - mq;
                #pragma unroll
                for (int jj = 0; jj < 8; ++jj) {
                    float d_ = dbase + (float)jj;
                    float p = __expf(-sq * d_ * d_);
                    lsum += p;
                    pfrag[jj] = (short)f2bf(p);
                }
                int slotx = (((kk >> 3) + lhi) ^ (lr & 7)) << 3;
                #pragma unroll
                for (int df = 0; df < 4; ++df) {
                    bf16x8 vf = *(const bf16x8*)&Vs[cur][(df * 16 + lr) * 64 + slotx];
                    acc[df] = __builtin_amdgcn_mfma_f32_16x16x32_bf16(pfrag, vf, acc[df], 0, 0, 0);
                }
            }
        }
        __syncthreads();
    }

    lsum += __shfl_xor(lsum, 16, 64);
    lsum += __shfl_xor(lsum, 32, 64);

    int slot_base = qb * 128 + wid * 16;
    #pragma unroll
    for (int r_ = 0; r_ < 4; ++r_) {
        int qr = lhi * 4 + r_;
        float inv = 1.f / __shfl(lsum, qr, 64);
        int qo = perm[bk * MM + slot_base + qr];
        long orow = ((long)b * MM + qo) * HSZ + head * DH;
        #pragma unroll
        for (int df = 0; df < 4; ++df)
            att[orow + df * 16 + lr] = f2bf(acc[df][r_] * inv);
    }
}

extern "C" void kernel_launch(void* const* d_in, const int* in_sizes, int n_in,
                              void* d_out, int out_size, void* d_ws, size_t ws_size,
                              hipStream_t stream) {
    (void)in_sizes; (void)n_in; (void)out_size; (void)ws_size;
    const float* h     = (const float*)d_in[0];   // (2, 2048, 1024)
    const float* Wspan = (const float*)d_in[1];   // (32, 1024)
    const float* Wval  = (const float*)d_in[2];   // (1024, 1024)
    const float* Wout  = (const float*)d_in[3];   // (1024, 1024)
    float* out = (float*)d_out;                   // (2, 2048, 1024) f32

    char* ws = (char*)d_ws;
    unsigned short* h_bf    = (unsigned short*)(ws);               // 8 MB
    unsigned short* Wval_bf = (unsigned short*)(ws +  8388608);    // 2 MB
    unsigned short* Wout_bf = (unsigned short*)(ws + 10485760);    // 2 MB
    unsigned short* hvT     = (unsigned short*)(ws + 12582912);    // 8 MB
    unsigned short* att     = (unsigned short*)(ws + 20971520);    // 8 MB
    float*          mean_   = (float*)(ws + 29360128);             // 256 KB
    float*          soft_   = (float*)(ws + 29622272);             // 256 KB
    int*            perm    = (int*)(ws + 29884416);               // 256 KB

    // 1. span-as-GEMM (64 blocks) || h/Wval/Wout converts (1536 blocks)
    pre_fused<<<1600, 256, 0, stream>>>(h, Wspan, Wval, Wout,
                                        mean_, soft_, h_bf, Wval_bf, Wout_bf);

    // 2. value GEMM (1024 blocks, 64x64 tiles) + row sort (32 blocks)
    vgemm_sort<<<1056, 256, 0, stream>>>(Wval_bf, h_bf, hvT, mean_, perm);

    // 3. fused Gaussian attention -> att (B, M, HS) bf16
    attn_gauss<<<512, 512, 0, stream>>>(mean_, soft_, perm, hvT, att);

    // 4. output GEMM: out[b*2048+m][n] = sum_c att[b,m,c] * Wout[n,c]
    ogemm<<<1024, 256, 0, stream>>>(att, Wout_bf, out);
}

// Round 15
// 65.957 us; speedup vs baseline: 1.5187x; 1.0568x over previous
//
#include <hip/hip_runtime.h>
#include <hip/hip_bf16.h>

// Problem constants (B=2, M=2048, HS=1024, K=16 heads, D=64)
#define MM   2048
#define HSZ  1024
#define KH   16
#define DH   64

typedef __attribute__((ext_vector_type(8))) short bf16x8;
typedef __attribute__((ext_vector_type(4))) float f32x4;
typedef __attribute__((ext_vector_type(8))) unsigned short u16x8;

#define GLOAD_LDS16(gp, lp) \
    __builtin_amdgcn_global_load_lds( \
        (const __attribute__((address_space(1))) unsigned int*)(gp), \
        (__attribute__((address_space(3))) unsigned int*)(lp), 16, 0, 0)

__device__ __forceinline__ unsigned short f2bf(float x) {
    union { float f; unsigned u; } v; v.f = x;
    unsigned r = v.u + 0x7FFFu + ((v.u >> 16) & 1u);
    return (unsigned short)(r >> 16);
}

// ================= L1: span split-K MFMA (blocks 0..255) || converts (256..1791) =================
// span: s = h.w via bf16-split 3-product (hi*whi + hi*wlo + lo*whi), f32 MFMA accum.
// 256 blocks x 16 rows; wave w of 4 owns K-quarter [w*256,(w+1)*256) -> 1024 indep waves,
// 8 K-steps each. No LDS staging (each element read once); 8KB LDS tree-reduce of partials.
__global__ __launch_bounds__(256) void pre_fused(
    const float* __restrict__ h, const float* __restrict__ Wspan,
    const float* __restrict__ Wval, const float* __restrict__ Wout,
    float* __restrict__ mean_, float* __restrict__ soft_,
    unsigned short* __restrict__ h_bf,
    unsigned short* __restrict__ Wval_bf, unsigned short* __restrict__ Wout_bf)
{
    __shared__ float red[4][16][33];         // [kq][m-row][o], +1 pad
    int t = threadIdx.x;

    if (blockIdx.x >= 256) {                 // ---- converts: h/Wval/Wout -> bf16 ----
        int bid = blockIdx.x - 256;
        #pragma unroll
        for (int i = 0; i < 4; ++i) {
            int fi = bid * 1024 + i * 256 + t;   // float4 id, 0..1572863
            const float* in; unsigned short* out; int off;
            if (fi < 1048576)      { in = h;    out = h_bf;    off = fi; }
            else if (fi < 1310720) { in = Wval; out = Wval_bf; off = fi - 1048576; }
            else                   { in = Wout; out = Wout_bf; off = fi - 1310720; }
            float4 v = *(const float4*)(in + (long)off * 4);
            ushort4 o4;
            o4.x = f2bf(v.x); o4.y = f2bf(v.y); o4.z = f2bf(v.z); o4.w = f2bf(v.w);
            *(ushort4*)(out + (long)off * 4) = o4;
        }
        return;
    }

    // ---- span block: 16 rows, wave = K-quarter ----
    int blk = blockIdx.x;
    int wid = t >> 6, l = t & 63;
    int lr = l & 15, lhi = l >> 4;
    int m0 = blk * 16;
    const float* hrow = h + (long)(m0 + lr) * HSZ + wid * 256;

    f32x4 acc[2] = {};

    #define SPLIT8(af_, hh_, hl_) { \
        _Pragma("unroll") for (int j_ = 0; j_ < 8; ++j_) { \
            unsigned short hu_ = f2bf(af_[j_]); \
            union { unsigned u; float f; } cv_; cv_.u = (unsigned)hu_ << 16; \
            hh_[j_] = (short)hu_; hl_[j_] = (short)f2bf(af_[j_] - cv_.f); } }

    #pragma unroll
    for (int ks = 0; ks < 8; ++ks) {
        int k0 = ks * 32 + lhi * 8;
        float4 a0 = *(const float4*)(hrow + k0);
        float4 a1 = *(const float4*)(hrow + k0 + 4);
        float af[8] = {a0.x, a0.y, a0.z, a0.w, a1.x, a1.y, a1.z, a1.w};
        bf16x8 hh, hl;
        SPLIT8(af, hh, hl);
        #pragma unroll
        for (int ct = 0; ct < 2; ++ct) {
            const float* wrow = Wspan + (long)(ct * 16 + lr) * HSZ + wid * 256 + k0;
            float4 w0 = *(const float4*)wrow;
            float4 w1 = *(const float4*)(wrow + 4);
            float wf[8] = {w0.x, w0.y, w0.z, w0.w, w1.x, w1.y, w1.z, w1.w};
            bf16x8 wh, wl;
            SPLIT8(wf, wh, wl);
            acc[ct] = __builtin_amdgcn_mfma_f32_16x16x32_bf16(hh, wh, acc[ct], 0, 0, 0);
            acc[ct] = __builtin_amdgcn_mfma_f32_16x16x32_bf16(hh, wl, acc[ct], 0, 0, 0);
            acc[ct] = __builtin_amdgcn_mfma_f32_16x16x32_bf16(hl, wh, acc[ct], 0, 0, 0);
        }
    }
    #undef SPLIT8

    // partials -> LDS  (D layout: row = lhi*4 + r_, col = lr)
    #pragma unroll
    for (int ct = 0; ct < 2; ++ct)
        #pragma unroll
        for (int r_ = 0; r_ < 4; ++r_)
            red[wid][lhi * 4 + r_][ct * 16 + lr] = acc[ct][r_];
    __syncthreads();

    // reduce 4 quarters + activation; thread t -> (row t>>4, o = t&15 and +16)
    int r = t >> 4, o2 = t & 15;
    #pragma unroll
    for (int half = 0; half < 2; ++half) {
        int o = half * 16 + o2;
        float s = red[0][r][o] + red[1][r][o] + red[2][r][o] + red[3][r][o];
        int m = m0 + r;
        int bb = m >> 11, mm = m & 2047;
        int bk = bb * KH + (o >> 1);
        if (!(o & 1)) mean_[bk * MM + mm] = (1.f / (1.f + __expf(-s))) * (float)MM;
        else          soft_[bk * MM + mm] = (s > 15.f) ? s : log1pf(__expf(s));
    }
}

// ---------------- shared GEMM core, 64x64 tile (R11, unchanged) ----------------
#define SROW(li) ((li) >> 3)
#define SCOL(li) ((((li) & 7) ^ (SROW(li) & 7)) * 8)

template<int STORE_BF16>
__device__ __forceinline__ void gemm_core64(
    unsigned short* __restrict__ AsB, unsigned short* __restrict__ BsB,   // each [2][4096]
    const unsigned short* __restrict__ A, const unsigned short* __restrict__ Bm,
    void* __restrict__ Cv, int N, int Kd,
    int bx, int by, int bz, long aZ, long bZ, long cZ)
{
    const unsigned short* Ab = A  + bz * aZ;
    const unsigned short* Bb = Bm + bz * bZ;
    long czoff = bz * cZ;
    int row0 = by * 64;
    int col0 = bx * 64;
    int t = threadIdx.x;
    int wid = t >> 6, l = t & 63;
    int wr = wid >> 1, wc = wid & 1;
    int lr = l & 15, lhi = l >> 4;

    #define STAGE64(buf, k0s) do { \
        unsigned short* As_ = AsB + (buf) * 4096; \
        unsigned short* Bs_ = BsB + (buf) * 4096; \
        int a0 = t, a1 = t + 256; \
        GLOAD_LDS16(Ab + (long)(row0 + SROW(a0)) * Kd + (k0s) + SCOL(a0), As_ + a0 * 8); \
        GLOAD_LDS16(Ab + (long)(row0 + SROW(a1)) * Kd + (k0s) + SCOL(a1), As_ + a1 * 8); \
        GLOAD_LDS16(Bb + (long)(col0 + SROW(a0)) * Kd + (k0s) + SCOL(a0), Bs_ + a0 * 8); \
        GLOAD_LDS16(Bb + (long)(col0 + SROW(a1)) * Kd + (k0s) + SCOL(a1), Bs_ + a1 * 8); \
    } while (0)

    f32x4 acc[2][2] = {};
    int nk = Kd >> 6;

    STAGE64(0, 0);

    for (int ks = 0; ks < nk; ++ks) {
        int cur = ks & 1;
        if (ks + 1 < nk) {
            STAGE64(cur ^ 1, (ks + 1) << 6);
            asm volatile("s_waitcnt vmcnt(4)" ::: "memory");
        } else {
            asm volatile("s_waitcnt vmcnt(0)" ::: "memory");
        }
        __builtin_amdgcn_s_barrier();

        bf16x8 af[2][2], bfr[2][2];
        #pragma unroll
        for (int kk = 0; kk < 2; ++kk) {
            int slotx = ((kk * 4 + lhi) ^ (lr & 7)) << 3;
            #pragma unroll
            for (int i = 0; i < 2; ++i)
                af[kk][i] = *(const bf16x8*)(AsB + cur * 4096 + (wr * 32 + i * 16 + lr) * 64 + slotx);
            #pragma unroll
            for (int j = 0; j < 2; ++j)
                bfr[kk][j] = *(const bf16x8*)(BsB + cur * 4096 + (wc * 32 + j * 16 + lr) * 64 + slotx);
        }
        asm volatile("s_waitcnt lgkmcnt(0)" ::: "memory");
        __builtin_amdgcn_sched_barrier(0);
        __builtin_amdgcn_s_barrier();

        #pragma unroll
        for (int kk = 0; kk < 2; ++kk)
            #pragma unroll
            for (int i = 0; i < 2; ++i)
                #pragma unroll
                for (int j = 0; j < 2; ++j)
                    acc[i][j] = __builtin_amdgcn_mfma_f32_16x16x32_bf16(af[kk][i], bfr[kk][j], acc[i][j], 0, 0, 0);
    }
    #undef STAGE64

    #pragma unroll
    for (int i = 0; i < 2; ++i) {
        int rbase = row0 + wr * 32 + i * 16 + lhi * 4;
        #pragma unroll
        for (int j = 0; j < 2; ++j) {
            int cidx = col0 + wc * 32 + j * 16 + lr;
            #pragma unroll
            for (int r_ = 0; r_ < 4; ++r_) {
                long idx = czoff + (long)(rbase + r_) * N + cidx;
                if (STORE_BF16) ((unsigned short*)Cv)[idx] = f2bf(acc[i][j][r_]);
                else            ((float*)Cv)[idx] = acc[i][j][r_];
            }
        }
    }
}

// ---------------- deterministic counting sort of rows by mean/64 (one bk per call) ----------------
__device__ void sort_core(char* smem, const float* __restrict__ mean_,
                          int* __restrict__ perm, int bk)
{
    unsigned short (*hist)[257] = (unsigned short(*)[257])smem;
    int* binTot = (int*)(smem + 16448);
    int* binStart = binTot + 32;
    int t = threadIdx.x;
    int bins[8];
    #pragma unroll
    for (int i = 0; i < 8; ++i) {
        float mq = mean_[bk * MM + t * 8 + i];
        int b = (int)(mq * (1.f / 64.f));
        bins[i] = min(31, max(0, b));
    }
    for (int b = 0; b < 32; ++b) hist[b][t] = 0;
    __syncthreads();
    #pragma unroll
    for (int i = 0; i < 8; ++i) hist[bins[i]][t]++;
    __syncthreads();
    int w = t >> 6, l = t & 63;
    for (int b = w * 8; b < w * 8 + 8; ++b) {
        int carry = 0;
        for (int g = 0; g < 4; ++g) {
            int v = (int)hist[b][g * 64 + l];
            int x = v;
            #pragma unroll
            for (int off = 1; off < 64; off <<= 1) {
                int y = __shfl_up(x, off, 64);
                if (l >= off) x += y;
            }
            hist[b][g * 64 + l] = (unsigned short)(x - v + carry);
            carry += __shfl(x, 63, 64);
        }
        if (l == 0) binTot[b] = carry;
    }
    __syncthreads();
    if (t == 0) {
        int s = 0;
        for (int b = 0; b < 32; ++b) { binStart[b] = s; s += binTot[b]; }
    }
    __syncthreads();
    #pragma unroll
    for (int i = 0; i < 8; ++i) {
        int b = bins[i];
        int prior = 0;
        #pragma unroll
        for (int j = 0; j < 8; ++j) if (j < i && bins[j] == b) prior++;
        int pos = binStart[b] + (int)hist[b][t] + prior;
        perm[bk * MM + pos] = t * 8 + i;
    }
}

// ---------------- value GEMM (blocks 0..1023) + sort (blocks 1024..1055) ----------------
__global__ __launch_bounds__(256) void vgemm_sort(
    const unsigned short* __restrict__ Wval_bf, const unsigned short* __restrict__ h_bf,
    unsigned short* __restrict__ hvT,
    const float* __restrict__ mean_, int* __restrict__ perm)
{
    __shared__ __align__(16) char smem[32768];
    int f = blockIdx.x;
    if (f < 1024) {
        int swz = (f & 7) * 128 + (f >> 3);
        int by = swz & 15, r = swz >> 4;
        int bx = r & 31, bz = r >> 5;
        gemm_core64<1>((unsigned short*)smem, (unsigned short*)(smem + 16384),
                       Wval_bf, h_bf, hvT, MM, HSZ, bx, by, bz,
                       0L, (long)MM * HSZ, (long)HSZ * MM);
    } else {
        sort_core(smem, mean_, perm, f - 1024);
    }
}

// ---------------- output GEMM standalone ----------------
__global__ __launch_bounds__(256) void ogemm(
    const unsigned short* __restrict__ att, const unsigned short* __restrict__ Wout_bf,
    float* __restrict__ out)
{
    __shared__ __align__(16) unsigned short As[2][4096];
    __shared__ __align__(16) unsigned short Bs[2][4096];
    int f = blockIdx.x;
    int swz = (f & 7) * 128 + (f >> 3);
    int bx = swz & 15, by = (swz >> 4) & 63;
    gemm_core64<0>(&As[0][0], &Bs[0][0], att, Wout_bf, out, HSZ, HSZ,
                   bx, by, 0, 0L, 0L, 0L);
}

// ---------------- fused Gaussian attention over mean-sorted rows (dynamic k-range) ----------------
__global__ __launch_bounds__(512) void attn_gauss(
    const float* __restrict__ mean_, const float* __restrict__ soft_,
    const int* __restrict__ perm,
    const unsigned short* __restrict__ hvT, unsigned short* __restrict__ att)
{
    __shared__ __align__(16) unsigned short Vs[2][64 * 64];
    __shared__ float red[2][8];
    int flat = blockIdx.x;                   // 0..511
    int swz = (flat & 7) * 64 + (flat >> 3); // XCD-chunked bijection
    int bk = swz >> 4;                       // 0..31
    int qb = swz & 15;                       // 0..15
    int t = threadIdx.x, wid = t >> 6, l = t & 63;
    int b = bk >> 4, head = bk & 15;
    int lr = l & 15, lhi = l >> 4;
    int slot = qb * 128 + wid * 16 + lr;
    int q = perm[bk * MM + slot];
    float mq  = mean_[bk * MM + q];
    float sq  = soft_[bk * MM + q];
    const unsigned short* Vbase = hvT + (long)bk * DH * MM;

    float w = __fsqrt_rn(50.f / sq);
    float lo = mq - w, hi = mq + w;
    #pragma unroll
    for (int off = 1; off < 64; off <<= 1) {
        lo = fminf(lo, __shfl_xor(lo, off, 64));
        hi = fmaxf(hi, __shfl_xor(hi, off, 64));
    }
    if (l == 0) { red[0][wid] = lo; red[1][wid] = hi; }
    __syncthreads();
    float blo = red[0][0], bhi = red[1][0];
    #pragma unroll
    for (int i = 1; i < 8; ++i) {
        blo = fminf(blo, red[0][i]);
        bhi = fmaxf(bhi, red[1][i]);
    }
    blo = fmaxf(blo, 0.f);
    bhi = fmaxf(fminf(bhi, 2047.f), 0.f);
    int kt0 = ((int)blo) >> 6;
    int kt1 = ((int)bhi) >> 6;
    if (kt1 < kt0) kt1 = kt0;

    int sr = t >> 3;
    int sc = (((t & 7) ^ (sr & 7)) * 8);

    f32x4 acc[4] = {};
    float lsum = 0.f;
    int jlane0 = lhi * 8;

    GLOAD_LDS16(Vbase + (long)sr * MM + (kt0 << 6) + sc, &Vs[0][t * 8]);
    __syncthreads();

    for (int kt = kt0; kt <= kt1; ++kt) {
        int cur = (kt - kt0) & 1;
        int k0 = kt << 6;
        if (kt < kt1)
            GLOAD_LDS16(Vbase + (long)sr * MM + (k0 + 64) + sc, &Vs[cur ^ 1][t * 8]);

        float dmin = fmaxf(fmaxf((float)k0 - mq, mq - (float)(k0 + 63)), 0.f);
        bool active = (sq * dmin * dmin) < 50.f;   // exp(-50) ~ 2e-22
        if (__ballot(active)) {
            #pragma unroll
            for (int kk = 0; kk < 64; kk += 32) {
                bf16x8 pfrag;
                float dbase = (float)(k0 + kk + jlane0) - mq;
                #pragma unroll
                for (int jj = 0; jj < 8; ++jj) {
                    float d_ = dbase + (float)jj;
                    float p = __expf(-sq * d_ * d_);
                    lsum += p;
                    pfrag[jj] = (short)f2bf(p);
                }
                int slotx = (((kk >> 3) + lhi) ^ (lr & 7)) << 3;
                #pragma unroll
                for (int df = 0; df < 4; ++df) {
                    bf16x8 vf = *(const bf16x8*)&Vs[cur][(df * 16 + lr) * 64 + slotx];
                    acc[df] = __builtin_amdgcn_mfma_f32_16x16x32_bf16(pfrag, vf, acc[df], 0, 0, 0);
                }
            }
        }
        __syncthreads();
    }

    lsum += __shfl_xor(lsum, 16, 64);
    lsum += __shfl_xor(lsum, 32, 64);

    int slot_base = qb * 128 + wid * 16;
    #pragma unroll
    for (int r_ = 0; r_ < 4; ++r_) {
        int qr = lhi * 4 + r_;
        float inv = 1.f / __shfl(lsum, qr, 64);
        int qo = perm[bk * MM + slot_base + qr];
        long orow = ((long)b * MM + qo) * HSZ + head * DH;
        #pragma unroll
        for (int df = 0; df < 4; ++df)
            att[orow + df * 16 + lr] = f2bf(acc[df][r_] * inv);
    }
}

extern "C" void kernel_launch(void* const* d_in, const int* in_sizes, int n_in,
                              void* d_out, int out_size, void* d_ws, size_t ws_size,
                              hipStream_t stream) {
    (void)in_sizes; (void)n_in; (void)out_size; (void)ws_size;
    const float* h     = (const float*)d_in[0];   // (2, 2048, 1024)
    const float* Wspan = (const float*)d_in[1];   // (32, 1024)
    const float* Wval  = (const float*)d_in[2];   // (1024, 1024)
    const float* Wout  = (const float*)d_in[3];   // (1024, 1024)
    float* out = (float*)d_out;                   // (2, 2048, 1024) f32

    char* ws = (char*)d_ws;
    unsigned short* h_bf    = (unsigned short*)(ws);               // 8 MB
    unsigned short* Wval_bf = (unsigned short*)(ws +  8388608);    // 2 MB
    unsigned short* Wout_bf = (unsigned short*)(ws + 10485760);    // 2 MB
    unsigned short* hvT     = (unsigned short*)(ws + 12582912);    // 8 MB
    unsigned short* att     = (unsigned short*)(ws + 20971520);    // 8 MB
    float*          mean_   = (float*)(ws + 29360128);             // 256 KB
    float*          soft_   = (float*)(ws + 29622272);             // 256 KB
    int*            perm    = (int*)(ws + 29884416);               // 256 KB

    // 1. span split-K MFMA (256 blocks) || h/Wval/Wout converts (1536 blocks)
    pre_fused<<<1792, 256, 0, stream>>>(h, Wspan, Wval, Wout,
                                        mean_, soft_, h_bf, Wval_bf, Wout_bf);

    // 2. value GEMM (1024 blocks, 64x64 tiles) + row sort (32 blocks)
    vgemm_sort<<<1056, 256, 0, stream>>>(Wval_bf, h_bf, hvT, mean_, perm);

    // 3. fused Gaussian attention -> att (B, M, HS) bf16
    attn_gauss<<<512, 512, 0, stream>>>(mean_, soft_, perm, hvT, att);

    // 4. output GEMM: out[b*2048+m][n] = sum_c att[b,m,c] * Wout[n,c]
    ogemm<<<1024, 256, 0, stream>>>(att, Wout_bf, out);
}